// Round 9
// baseline (652.718 us; speedup 1.0000x reference)
//
#include <hip/hip_runtime.h>
#include <stdint.h>

// Problem: B=4, T=2048, D_IN=512, D_OUT=512, N_FILT=24.
// Inputs fp32 (runtime-detected, bf16 fallback). Output fp32.
// out[b,t,o] = sum_n phi[t,n] * cumsum_t( phi[t,n] * (M[n] @ x[b,t,:]) )[o]
#define BQ 4
#define TT 2048
#define DF 512
#define DOUT 512
#define NF 24

typedef __attribute__((ext_vector_type(8))) short short8;
typedef __attribute__((ext_vector_type(4))) float f32x4;

typedef __attribute__((address_space(3))) uint8_t       lds_u8;
typedef __attribute__((address_space(1))) const uint8_t glb_u8;

__device__ __forceinline__ float bf2f(unsigned short u) {
    union { unsigned int i; float f; } v; v.i = ((unsigned int)u) << 16; return v.f;
}
__device__ __forceinline__ unsigned short f2bf(float f) {
    union { float f; unsigned int i; } v; v.f = f;
    unsigned int r = v.i + 0x7FFFu + ((v.i >> 16) & 1u);  // RNE
    return (unsigned short)(r >> 16);
}

// ---------------------------------------------------------------------------
// Dtype sniffer (flag=1 => fp32 inputs).
// ---------------------------------------------------------------------------
__device__ __forceinline__ int plaus16(unsigned int h) {
    unsigned int e = (h >> 7) & 0xffu;
    return (e >= 97u && e <= 141u) || ((h & 0x7fffu) == 0u);
}

__global__ void k_detect(const unsigned int* __restrict__ X, int* __restrict__ flag)
{
    const int lane = threadIdx.x;  // 64 threads, 1 block
    int cnt = 0;
#pragma unroll
    for (int i = 0; i < 4; ++i) {
        unsigned int w = X[lane * 4 + i];
        cnt += (plaus16(w >> 16) && plaus16(w & 0xffffu)) ? 1 : 0;
    }
    for (int off = 32; off > 0; off >>= 1) cnt += __shfl_down(cnt, off);
    if (lane == 0) *flag = (cnt < 180) ? 1 : 0;
}

// ---------------------------------------------------------------------------
// One-time conversions: X/M -> bf16 workspace copies, filters -> fp32.
// ---------------------------------------------------------------------------
__global__ __launch_bounds__(256) void k_convert(
    const void* __restrict__ src, unsigned short* __restrict__ dst,
    const int* __restrict__ flag, int n4)
{
    const int isf32 = *flag;
    int i = blockIdx.x * 256 + threadIdx.x;
    const int stride = gridDim.x * 256;
    for (; i < n4; i += stride) {
        ushort4 o;
        if (isf32) {
            float4 v = ((const float4*)src)[i];
            o.x = f2bf(v.x); o.y = f2bf(v.y); o.z = f2bf(v.z); o.w = f2bf(v.w);
        } else {
            o = ((const ushort4*)src)[i];
        }
        ((ushort4*)dst)[i] = o;
    }
}

__global__ __launch_bounds__(256) void k_convf(
    const void* __restrict__ src, float* __restrict__ dst,
    const int* __restrict__ flag, int n)
{
    const int isf32 = *flag;
    int i = blockIdx.x * 256 + threadIdx.x;
    const int stride = gridDim.x * 256;
    for (; i < n; i += stride)
        dst[i] = isf32 ? ((const float*)src)[i]
                       : bf2f(((const unsigned short*)src)[i]);
}

// ---------------------------------------------------------------------------
// FAST GEMM (m97 pattern): pure bf16 inputs, global_load_lds width-16
// staging, 128x128 tile, BK=32, 16x16x32 MFMA, phi-scaled bf16 epilogue.
// grid (RT/128, 4, NF), block 256.
// ---------------------------------------------------------------------------
__global__ __launch_bounds__(256, 2) void k_gemm_fast(
    const unsigned short* __restrict__ X,   // bf16 [B*T, DF]
    const unsigned short* __restrict__ Mw,  // bf16 [NF][DOUT][DF]
    const float* __restrict__ Fw,           // fp32 [TT][NF]
    unsigned short* __restrict__ Z,         // bf16 [rl][n][512]
    int r0)
{
    __shared__ unsigned short sA[128 * 32];
    __shared__ unsigned short sB[128 * 32];
    __shared__ unsigned short sC[128 * 136];
    __shared__ float sPhi[128];

    const int tid  = threadIdx.x;
    const int lane = tid & 63;
    const int w    = tid >> 6;
    const int wm   = w & 1, wn = w >> 1;
    const int tm   = blockIdx.x;
    const int on0  = blockIdx.y * 128;
    const int n    = blockIdx.z;

    const int rowg0 = r0 + tm * 128;
    if (tid < 128)
        sPhi[tid] = Fw[((rowg0 + tid) & (TT - 1)) * NF + n];

    const unsigned short* Ag = X + (size_t)rowg0 * DF;
    const unsigned short* Bg = Mw + (size_t)n * DOUT * DF + (size_t)on0 * DF;

    f32x4 acc[4][4];
#pragma unroll
    for (int i = 0; i < 4; i++)
#pragma unroll
        for (int j = 0; j < 4; j++) acc[i][j] = (f32x4){0.f, 0.f, 0.f, 0.f};

    for (int kt = 0; kt < DF / 32; ++kt) {
        __syncthreads();
        const unsigned short* Ak = Ag + kt * 32;
        const unsigned short* Bk = Bg + kt * 32;
#pragma unroll
        for (int i = 0; i < 2; ++i) {
            const int cbase = i * 256 + w * 64;   // wave-uniform 16B-chunk base
            const int c = cbase + lane;           // this lane's chunk, 0..511
            const int r = c >> 2, cc = c & 3;
            __builtin_amdgcn_global_load_lds(
                (const glb_u8*)(Ak + (size_t)r * DF + cc * 8),
                (lds_u8*)sA + cbase * 16, 16, 0, 0);
            __builtin_amdgcn_global_load_lds(
                (const glb_u8*)(Bk + (size_t)r * DF + cc * 8),
                (lds_u8*)sB + cbase * 16, 16, 0, 0);
        }
        __syncthreads();

        const int lr = lane & 15;
        const int lk = (lane >> 4) * 8;
        short8 a[4], b[4];
#pragma unroll
        for (int i = 0; i < 4; i++)
            a[i] = *(const short8*)&sA[(wm * 64 + i * 16 + lr) * 32 + lk];
#pragma unroll
        for (int j = 0; j < 4; j++)
            b[j] = *(const short8*)&sB[(wn * 64 + j * 16 + lr) * 32 + lk];
#pragma unroll
        for (int i = 0; i < 4; i++)
#pragma unroll
            for (int j = 0; j < 4; j++)
                acc[i][j] = __builtin_amdgcn_mfma_f32_16x16x32_bf16(
                    a[i], b[j], acc[i][j], 0, 0, 0);
    }

    // C/D layout (m89/m91-verified): col = lane&15, row = (lane>>4)*4 + reg
    const int rb = (lane >> 4) * 4;
#pragma unroll
    for (int i = 0; i < 4; i++)
#pragma unroll
        for (int j = 0; j < 4; j++)
#pragma unroll
            for (int r = 0; r < 4; r++) {
                int row = wm * 64 + i * 16 + rb + r;
                sC[row * 136 + wn * 64 + j * 16 + (lane & 15)] =
                    f2bf(acc[i][j][r] * sPhi[row]);
            }
    __syncthreads();
#pragma unroll
    for (int it = 0; it < 8; ++it) {
        int row = it * 16 + (tid >> 4);
        int col = (tid & 15) * 8;
        uint4 v = *(const uint4*)&sC[row * 136 + col];
        *(uint4*)&Z[((size_t)(tm * 128 + row) * NF + n) * 512 + on0 + col] = v;
    }
}

// ---------------------------------------------------------------------------
// SLOW GEMM (fallback for tiny ws): register staging + in-flight convert.
// ---------------------------------------------------------------------------
__global__ __launch_bounds__(256, 2) void k_gemm(
    const void* __restrict__ Xv, const void* __restrict__ Mv,
    const void* __restrict__ Fv, const int* __restrict__ flag,
    unsigned short* __restrict__ Z, int r0, int o0, int W)
{
    __shared__ unsigned short sA[128 * 32];
    __shared__ unsigned short sB[128 * 32];
    __shared__ unsigned short sC[128 * 136];
    __shared__ float sPhi[128];

    const int isf32 = *flag;
    const int tid  = threadIdx.x;
    const int lane = tid & 63;
    const int w    = tid >> 6;
    const int wm   = w & 1, wn = w >> 1;
    const int tm   = blockIdx.x;
    const int on0  = o0 + blockIdx.y * 128;
    const int n    = blockIdx.z;

    const int rowg0 = r0 + tm * 128;
    if (tid < 128) {
        int t = (rowg0 + tid) & (TT - 1);
        sPhi[tid] = isf32 ? ((const float*)Fv)[t * NF + n]
                          : bf2f(((const unsigned short*)Fv)[t * NF + n]);
    }

    const unsigned short* Ah = (const unsigned short*)Xv + (size_t)rowg0 * DF;
    const unsigned short* Bh = (const unsigned short*)Mv +
        (size_t)n * DOUT * DF + (size_t)on0 * DF;
    const float* Af = (const float*)Xv + (size_t)rowg0 * DF;
    const float* Bf = (const float*)Mv + (size_t)n * DOUT * DF + (size_t)on0 * DF;

    f32x4 acc[4][4];
#pragma unroll
    for (int i = 0; i < 4; i++)
#pragma unroll
        for (int j = 0; j < 4; j++) acc[i][j] = (f32x4){0.f, 0.f, 0.f, 0.f};

    for (int kt = 0; kt < DF / 32; ++kt) {
        __syncthreads();
        if (!isf32) {
            const unsigned short* Ak = Ah + kt * 32;
            const unsigned short* Bk = Bh + kt * 32;
#pragma unroll
            for (int i = 0; i < 2; ++i) {
                const int c = i * 256 + tid;
                const int r = c >> 2, cc = (c & 3) * 8;
                *(short8*)&sA[r * 32 + cc] = *(const short8*)(Ak + (size_t)r * DF + cc);
                *(short8*)&sB[r * 32 + cc] = *(const short8*)(Bk + (size_t)r * DF + cc);
            }
        } else {
            const float* Ak = Af + kt * 32;
            const float* Bk = Bf + kt * 32;
#pragma unroll
            for (int i = 0; i < 2; ++i) {
                const int c = i * 256 + tid;
                const int r = c >> 2, cc = (c & 3) * 8;
                float4 a0 = *(const float4*)(Ak + (size_t)r * DF + cc);
                float4 a1 = *(const float4*)(Ak + (size_t)r * DF + cc + 4);
                float4 b0 = *(const float4*)(Bk + (size_t)r * DF + cc);
                float4 b1 = *(const float4*)(Bk + (size_t)r * DF + cc + 4);
                short8 sa, sb;
                sa[0]=(short)f2bf(a0.x); sa[1]=(short)f2bf(a0.y);
                sa[2]=(short)f2bf(a0.z); sa[3]=(short)f2bf(a0.w);
                sa[4]=(short)f2bf(a1.x); sa[5]=(short)f2bf(a1.y);
                sa[6]=(short)f2bf(a1.z); sa[7]=(short)f2bf(a1.w);
                sb[0]=(short)f2bf(b0.x); sb[1]=(short)f2bf(b0.y);
                sb[2]=(short)f2bf(b0.z); sb[3]=(short)f2bf(b0.w);
                sb[4]=(short)f2bf(b1.x); sb[5]=(short)f2bf(b1.y);
                sb[6]=(short)f2bf(b1.z); sb[7]=(short)f2bf(b1.w);
                *(short8*)&sA[r * 32 + cc] = sa;
                *(short8*)&sB[r * 32 + cc] = sb;
            }
        }
        __syncthreads();

        const int lr = lane & 15;
        const int lk = (lane >> 4) * 8;
        short8 a[4], b[4];
#pragma unroll
        for (int i = 0; i < 4; i++)
            a[i] = *(const short8*)&sA[(wm * 64 + i * 16 + lr) * 32 + lk];
#pragma unroll
        for (int j = 0; j < 4; j++)
            b[j] = *(const short8*)&sB[(wn * 64 + j * 16 + lr) * 32 + lk];
#pragma unroll
        for (int i = 0; i < 4; i++)
#pragma unroll
            for (int j = 0; j < 4; j++)
                acc[i][j] = __builtin_amdgcn_mfma_f32_16x16x32_bf16(
                    a[i], b[j], acc[i][j], 0, 0, 0);
    }

    const int rb = (lane >> 4) * 4;
#pragma unroll
    for (int i = 0; i < 4; i++)
#pragma unroll
        for (int j = 0; j < 4; j++)
#pragma unroll
            for (int r = 0; r < 4; r++) {
                int row = wm * 64 + i * 16 + rb + r;
                sC[row * 136 + wn * 64 + j * 16 + (lane & 15)] =
                    f2bf(acc[i][j][r] * sPhi[row]);
            }
    __syncthreads();
#pragma unroll
    for (int it = 0; it < 8; ++it) {
        int row = it * 16 + (tid >> 4);
        int col = (tid & 15) * 8;
        uint4 v = *(const uint4*)&sC[row * 136 + col];
        *(uint4*)&Z[((size_t)(tm * 128 + row) * NF + n) * W + (on0 - o0) + col] = v;
    }
}

// ---------------------------------------------------------------------------
// Kernel 2a: chunk sums over CHs rows. grid (nch, NF), block W/2.
// ---------------------------------------------------------------------------
__global__ __launch_bounds__(256, 2) void k_csum(
    const unsigned short* __restrict__ Z, float* __restrict__ Cs,
    int W, int CHs)
{
    const int c = blockIdx.x, n = blockIdx.y, tid = threadIdx.x;
    const unsigned short* p = Z + ((size_t)(c * CHs) * NF + n) * W + tid * 2;
    float sx = 0.f, sy = 0.f;
#pragma unroll 8
    for (int t = 0; t < CHs; ++t) {
        unsigned int u = *(const unsigned int*)(p + (size_t)t * NF * W);
        sx += __uint_as_float(u << 16);
        sy += __uint_as_float(u & 0xffff0000u);
    }
    float2* q = (float2*)&Cs[((size_t)c * NF + n) * W + tid * 2];
    *q = make_float2(sx, sy);
}

// ---------------------------------------------------------------------------
// Kernel 2b: exclusive prefix over chunks + cross-pass carry Gc.
// grid (NF, W/128), block 64 (each thread one o-pair column).
// ---------------------------------------------------------------------------
__global__ __launch_bounds__(64, 4) void k_prefix(
    float* __restrict__ Cs, float* __restrict__ Gc, int W, int rr, int nch)
{
    const int n = blockIdx.x;
    const int pid = blockIdx.y * 64 + threadIdx.x;   // o-pair index, < W/2
    float rx = 0.f, ry = 0.f;
    if (rr != 0) {
        float2 g = *(const float2*)&Gc[(size_t)n * DOUT + pid * 2];
        rx = g.x; ry = g.y;
    }
    const size_t base = (size_t)n * W + pid * 2;
#pragma unroll 4
    for (int c = 0; c < nch; ++c) {
        float2* p = (float2*)&Cs[base + (size_t)c * NF * W];
        float2 v = *p;
        *p = make_float2(rx, ry);
        rx += v.x; ry += v.y;
    }
    *(float2*)&Gc[(size_t)n * DOUT + pid * 2] = make_float2(rx, ry);
}

// ---------------------------------------------------------------------------
// Kernel 2c: scan + filter-weighted reduce. Output fp32.
// Running state = 48 NAMED SCALARS via X-macro. r6/r7/r8 post-mortems:
// float[24] and ext_vector(24) locals with loop-variable subscripts are
// alloca'd at IR-gen; SROA runs before unrolling -> never promoted (VGPR 36/
// 32/40, scratch-bound 137/193/48 us). Named scalars are SSA by construction.
// grid (nch), block W/2.
// ---------------------------------------------------------------------------
#define NLIST(F) F(0) F(1) F(2) F(3) F(4) F(5) F(6) F(7) F(8) F(9) F(10) F(11) \
                 F(12) F(13) F(14) F(15) F(16) F(17) F(18) F(19) F(20) F(21) F(22) F(23)

__global__ __launch_bounds__(256, 2) void k_scan(
    const unsigned short* __restrict__ Z, const float* __restrict__ Cs,
    const float* __restrict__ Fw, float* __restrict__ Out,
    int r0, int o0, int W, int CHs)
{
    __shared__ float sPhi[32 * NF];
    const int cg = blockIdx.x, tid = threadIdx.x;
    const int t0g = r0 + cg * CHs;
    const int t0 = t0g & (TT - 1);
    for (int i = tid; i < CHs * NF; i += blockDim.x)
        sPhi[i] = Fw[(t0 + i / NF) * NF + (i % NF)];
    __syncthreads();

#define DECLG(n) float gx##n, gy##n;
    NLIST(DECLG)
#define INITG(n) { float2 v = *(const float2*)&Cs[((size_t)cg * NF + n) * W + tid * 2]; \
                   gx##n = v.x; gy##n = v.y; }
    NLIST(INITG)

    const unsigned short* zp = Z + ((size_t)cg * CHs * NF) * W + tid * 2;
    float* op = Out + (size_t)t0g * DOUT + o0 + tid * 2;
    for (int t = 0; t < CHs; ++t) {
        float ax = 0.f, ay = 0.f;
        const float* php = &sPhi[t * NF];
#define UPDG(n) { unsigned int u = *(const unsigned int*)(zp + (size_t)(n) * W); \
                  gx##n += __uint_as_float(u << 16); \
                  gy##n += __uint_as_float(u & 0xffff0000u); \
                  float ph = php[n]; ax += ph * gx##n; ay += ph * gy##n; }
        NLIST(UPDG)
        *(float2*)op = make_float2(ax, ay);
        zp += (size_t)NF * W;
        op += DOUT;
    }
}

// ---------------------------------------------------------------------------
extern "C" void kernel_launch(void* const* d_in, const int* in_sizes, int n_in,
                              void* d_out, int out_size, void* d_ws, size_t ws_size,
                              hipStream_t stream)
{
    const void* X = d_in[0]; const void* Fil = d_in[1]; const void* Mw = d_in[2];
    for (int i = 0; i < n_in && i < 3; ++i) {
        if (in_sizes[i] == BQ * TT * DF)        X   = d_in[i];
        else if (in_sizes[i] == TT * NF)        Fil = d_in[i];
        else if (in_sizes[i] == NF * DOUT * DF) Mw  = d_in[i];
    }
    float* Out = (float*)d_out;

    const size_t offF = 256;
    const size_t nbF  = (size_t)TT * NF * 4;
    const size_t off0 = offF + nbF;
    const size_t nbX  = (size_t)BQ * TT * DF * 2;    // 8.39 MB
    const size_t nbM  = (size_t)NF * DOUT * DF * 2;  // 12.58 MB
    const size_t nbGc = (size_t)NF * DOUT * 4;

    int* flag = (int*)d_ws;
    float* Fw = (float*)((char*)d_ws + offF);

    // Fast tier: (RT rows/pass, CHs scan-chunk). Prefer big RT, small CHs.
    static const int rts[5] = {2048, 1024, 512, 256, 128};
    static const int chss[3] = {8, 16, 32};
    int RT = 0, CHs = 32;
    for (int ri = 0; ri < 5 && RT == 0; ++ri)
        for (int ci = 0; ci < 3; ++ci) {
            int rt = rts[ri], ch = chss[ci];
            size_t need = off0 + nbX + nbM
                        + (size_t)rt * NF * 512 * 2
                        + (size_t)(rt / ch) * NF * 512 * 4 + nbGc;
            if (need <= ws_size) { RT = rt; CHs = ch; break; }
        }

    hipLaunchKernelGGL(k_detect, dim3(1), dim3(64), 0, stream,
                       (const unsigned int*)X, flag);
    hipLaunchKernelGGL(k_convf, dim3(192), dim3(256), 0, stream,
                       Fil, Fw, flag, TT * NF);

    if (RT > 0) {
        unsigned short* Xbf = (unsigned short*)((char*)d_ws + off0);
        unsigned short* Mbf = (unsigned short*)((char*)Xbf + nbX);
        unsigned short* Z   = (unsigned short*)((char*)Mbf + nbM);
        float* Cs = (float*)((char*)Z + (size_t)RT * NF * 512 * 2);
        float* Gc = (float*)((char*)Cs + (size_t)(RT / CHs) * NF * 512 * 4);

        hipLaunchKernelGGL(k_convert, dim3(2048), dim3(256), 0, stream,
                           X, Xbf, flag, BQ * TT * DF / 4);
        hipLaunchKernelGGL(k_convert, dim3(3072), dim3(256), 0, stream,
                           Mw, Mbf, flag, NF * DOUT * DF / 4);

        const int nrr = TT / RT, nch = RT / CHs;
        for (int b = 0; b < BQ; ++b) {
            for (int rr = 0; rr < nrr; ++rr) {
                const int r0 = b * TT + rr * RT;
                hipLaunchKernelGGL(k_gemm_fast, dim3(RT / 128, 4, NF), dim3(256),
                                   0, stream, Xbf, Mbf, Fw, Z, r0);
                hipLaunchKernelGGL(k_csum, dim3(nch, NF), dim3(256), 0, stream,
                                   Z, Cs, 512, CHs);
                hipLaunchKernelGGL(k_prefix, dim3(NF, 4), dim3(64), 0, stream,
                                   Cs, Gc, 512, rr, nch);
                hipLaunchKernelGGL(k_scan, dim3(nch), dim3(256), 0, stream,
                                   Z, Cs, Fw, Out, r0, 0, 512, CHs);
            }
        }
        return;
    }

    // Slow tiers (tiny ws): in-kernel convert GEMM, o-sliced, CH=32.
    static const int cRT[7] = {2048, 1024, 512, 256, 128, 128, 128};
    static const int cW[7]  = {512, 512, 512, 512, 512, 256, 128};
    int RTs = 128, W = 128;
    for (int ci = 0; ci < 7; ++ci) {
        size_t need = off0 + (size_t)cRT[ci] * NF * cW[ci] * 2
                    + (size_t)(cRT[ci] / 32) * NF * cW[ci] * 4 + nbGc;
        if (need <= ws_size) { RTs = cRT[ci]; W = cW[ci]; break; }
    }
    unsigned short* Z = (unsigned short*)((char*)d_ws + off0);
    float* Cs = (float*)((char*)Z + (size_t)RTs * NF * W * 2);
    float* Gc = (float*)((char*)Cs + (size_t)(RTs / 32) * NF * W * 4);

    const int nrr = TT / RTs, nch = RTs / 32;
    for (int b = 0; b < BQ; ++b) {
        for (int o0 = 0; o0 < DOUT; o0 += W) {
            for (int rr = 0; rr < nrr; ++rr) {
                const int r0 = b * TT + rr * RTs;
                hipLaunchKernelGGL(k_gemm, dim3(RTs / 128, W / 128, NF), dim3(256),
                                   0, stream, X, Mw, Fil, flag, Z, r0, o0, W);
                hipLaunchKernelGGL(k_csum, dim3(nch, NF), dim3(W / 2), 0, stream,
                                   Z, Cs, W, 32);
                hipLaunchKernelGGL(k_prefix, dim3(NF, W / 128), dim3(64), 0, stream,
                                   Cs, Gc, W, rr, nch);
                hipLaunchKernelGGL(k_scan, dim3(nch), dim3(W / 2), 0, stream,
                                   Z, Cs, Fw, Out, r0, o0, W, 32);
            }
        }
    }
}

// Round 10
// 457.935 us; speedup vs baseline: 1.4253x; 1.4253x over previous
//
#include <hip/hip_runtime.h>
#include <stdint.h>

// Problem: B=4, T=2048, D_IN=512, D_OUT=512, N_FILT=24.
// Inputs fp32 (runtime-detected, bf16 fallback). Output fp32.
// out[b,t,o] = sum_n phi[t,n] * cumsum_t( phi[t,n] * (M[n] @ x[b,t,:]) )[o]
#define BQ 4
#define TT 2048
#define DF 512
#define DOUT 512
#define NF 24

typedef __attribute__((ext_vector_type(8))) short short8;
typedef __attribute__((ext_vector_type(4))) float f32x4;

typedef __attribute__((address_space(3))) uint8_t       lds_u8;
typedef __attribute__((address_space(1))) const uint8_t glb_u8;

__device__ __forceinline__ float bf2f(unsigned short u) {
    union { unsigned int i; float f; } v; v.i = ((unsigned int)u) << 16; return v.f;
}
__device__ __forceinline__ unsigned short f2bf(float f) {
    union { float f; unsigned int i; } v; v.f = f;
    unsigned int r = v.i + 0x7FFFu + ((v.i >> 16) & 1u);  // RNE
    return (unsigned short)(r >> 16);
}

// ---------------------------------------------------------------------------
// Dtype sniffer (flag=1 => fp32 inputs).
// ---------------------------------------------------------------------------
__device__ __forceinline__ int plaus16(unsigned int h) {
    unsigned int e = (h >> 7) & 0xffu;
    return (e >= 97u && e <= 141u) || ((h & 0x7fffu) == 0u);
}

__global__ void k_detect(const unsigned int* __restrict__ X, int* __restrict__ flag)
{
    const int lane = threadIdx.x;  // 64 threads, 1 block
    int cnt = 0;
#pragma unroll
    for (int i = 0; i < 4; ++i) {
        unsigned int w = X[lane * 4 + i];
        cnt += (plaus16(w >> 16) && plaus16(w & 0xffffu)) ? 1 : 0;
    }
    for (int off = 32; off > 0; off >>= 1) cnt += __shfl_down(cnt, off);
    if (lane == 0) *flag = (cnt < 180) ? 1 : 0;
}

// ---------------------------------------------------------------------------
// One-time conversions: X/M -> bf16 workspace copies, filters -> fp32.
// ---------------------------------------------------------------------------
__global__ __launch_bounds__(256) void k_convert(
    const void* __restrict__ src, unsigned short* __restrict__ dst,
    const int* __restrict__ flag, int n4)
{
    const int isf32 = *flag;
    int i = blockIdx.x * 256 + threadIdx.x;
    const int stride = gridDim.x * 256;
    for (; i < n4; i += stride) {
        ushort4 o;
        if (isf32) {
            float4 v = ((const float4*)src)[i];
            o.x = f2bf(v.x); o.y = f2bf(v.y); o.z = f2bf(v.z); o.w = f2bf(v.w);
        } else {
            o = ((const ushort4*)src)[i];
        }
        ((ushort4*)dst)[i] = o;
    }
}

__global__ __launch_bounds__(256) void k_convf(
    const void* __restrict__ src, float* __restrict__ dst,
    const int* __restrict__ flag, int n)
{
    const int isf32 = *flag;
    int i = blockIdx.x * 256 + threadIdx.x;
    const int stride = gridDim.x * 256;
    for (; i < n; i += stride)
        dst[i] = isf32 ? ((const float*)src)[i]
                       : bf2f(((const unsigned short*)src)[i]);
}

// ---------------------------------------------------------------------------
// FAST GEMM (m97 pattern): pure bf16 inputs, global_load_lds width-16
// staging, 128x128 tile, BK=32, 16x16x32 MFMA, phi-scaled bf16 epilogue.
// grid (RT/128, 4, NF), block 256.
// ---------------------------------------------------------------------------
__global__ __launch_bounds__(256, 2) void k_gemm_fast(
    const unsigned short* __restrict__ X,   // bf16 [B*T, DF]
    const unsigned short* __restrict__ Mw,  // bf16 [NF][DOUT][DF]
    const float* __restrict__ Fw,           // fp32 [TT][NF]
    unsigned short* __restrict__ Z,         // bf16 [rl][n][512]
    int r0)
{
    __shared__ unsigned short sA[128 * 32];
    __shared__ unsigned short sB[128 * 32];
    __shared__ unsigned short sC[128 * 136];
    __shared__ float sPhi[128];

    const int tid  = threadIdx.x;
    const int lane = tid & 63;
    const int w    = tid >> 6;
    const int wm   = w & 1, wn = w >> 1;
    const int tm   = blockIdx.x;
    const int on0  = blockIdx.y * 128;
    const int n    = blockIdx.z;

    const int rowg0 = r0 + tm * 128;
    if (tid < 128)
        sPhi[tid] = Fw[((rowg0 + tid) & (TT - 1)) * NF + n];

    const unsigned short* Ag = X + (size_t)rowg0 * DF;
    const unsigned short* Bg = Mw + (size_t)n * DOUT * DF + (size_t)on0 * DF;

    f32x4 acc[4][4];
#pragma unroll
    for (int i = 0; i < 4; i++)
#pragma unroll
        for (int j = 0; j < 4; j++) acc[i][j] = (f32x4){0.f, 0.f, 0.f, 0.f};

    for (int kt = 0; kt < DF / 32; ++kt) {
        __syncthreads();
        const unsigned short* Ak = Ag + kt * 32;
        const unsigned short* Bk = Bg + kt * 32;
#pragma unroll
        for (int i = 0; i < 2; ++i) {
            const int cbase = i * 256 + w * 64;   // wave-uniform 16B-chunk base
            const int c = cbase + lane;           // this lane's chunk, 0..511
            const int r = c >> 2, cc = c & 3;
            __builtin_amdgcn_global_load_lds(
                (const glb_u8*)(Ak + (size_t)r * DF + cc * 8),
                (lds_u8*)sA + cbase * 16, 16, 0, 0);
            __builtin_amdgcn_global_load_lds(
                (const glb_u8*)(Bk + (size_t)r * DF + cc * 8),
                (lds_u8*)sB + cbase * 16, 16, 0, 0);
        }
        __syncthreads();

        const int lr = lane & 15;
        const int lk = (lane >> 4) * 8;
        short8 a[4], b[4];
#pragma unroll
        for (int i = 0; i < 4; i++)
            a[i] = *(const short8*)&sA[(wm * 64 + i * 16 + lr) * 32 + lk];
#pragma unroll
        for (int j = 0; j < 4; j++)
            b[j] = *(const short8*)&sB[(wn * 64 + j * 16 + lr) * 32 + lk];
#pragma unroll
        for (int i = 0; i < 4; i++)
#pragma unroll
            for (int j = 0; j < 4; j++)
                acc[i][j] = __builtin_amdgcn_mfma_f32_16x16x32_bf16(
                    a[i], b[j], acc[i][j], 0, 0, 0);
    }

    // C/D layout (m89/m91-verified): col = lane&15, row = (lane>>4)*4 + reg
    const int rb = (lane >> 4) * 4;
#pragma unroll
    for (int i = 0; i < 4; i++)
#pragma unroll
        for (int j = 0; j < 4; j++)
#pragma unroll
            for (int r = 0; r < 4; r++) {
                int row = wm * 64 + i * 16 + rb + r;
                sC[row * 136 + wn * 64 + j * 16 + (lane & 15)] =
                    f2bf(acc[i][j][r] * sPhi[row]);
            }
    __syncthreads();
#pragma unroll
    for (int it = 0; it < 8; ++it) {
        int row = it * 16 + (tid >> 4);
        int col = (tid & 15) * 8;
        uint4 v = *(const uint4*)&sC[row * 136 + col];
        *(uint4*)&Z[((size_t)(tm * 128 + row) * NF + n) * 512 + on0 + col] = v;
    }
}

// ---------------------------------------------------------------------------
// SLOW GEMM (fallback for tiny ws): register staging + in-flight convert.
// ---------------------------------------------------------------------------
__global__ __launch_bounds__(256, 2) void k_gemm(
    const void* __restrict__ Xv, const void* __restrict__ Mv,
    const void* __restrict__ Fv, const int* __restrict__ flag,
    unsigned short* __restrict__ Z, int r0, int o0, int W)
{
    __shared__ unsigned short sA[128 * 32];
    __shared__ unsigned short sB[128 * 32];
    __shared__ unsigned short sC[128 * 136];
    __shared__ float sPhi[128];

    const int isf32 = *flag;
    const int tid  = threadIdx.x;
    const int lane = tid & 63;
    const int w    = tid >> 6;
    const int wm   = w & 1, wn = w >> 1;
    const int tm   = blockIdx.x;
    const int on0  = o0 + blockIdx.y * 128;
    const int n    = blockIdx.z;

    const int rowg0 = r0 + tm * 128;
    if (tid < 128) {
        int t = (rowg0 + tid) & (TT - 1);
        sPhi[tid] = isf32 ? ((const float*)Fv)[t * NF + n]
                          : bf2f(((const unsigned short*)Fv)[t * NF + n]);
    }

    const unsigned short* Ah = (const unsigned short*)Xv + (size_t)rowg0 * DF;
    const unsigned short* Bh = (const unsigned short*)Mv +
        (size_t)n * DOUT * DF + (size_t)on0 * DF;
    const float* Af = (const float*)Xv + (size_t)rowg0 * DF;
    const float* Bf = (const float*)Mv + (size_t)n * DOUT * DF + (size_t)on0 * DF;

    f32x4 acc[4][4];
#pragma unroll
    for (int i = 0; i < 4; i++)
#pragma unroll
        for (int j = 0; j < 4; j++) acc[i][j] = (f32x4){0.f, 0.f, 0.f, 0.f};

    for (int kt = 0; kt < DF / 32; ++kt) {
        __syncthreads();
        if (!isf32) {
            const unsigned short* Ak = Ah + kt * 32;
            const unsigned short* Bk = Bh + kt * 32;
#pragma unroll
            for (int i = 0; i < 2; ++i) {
                const int c = i * 256 + tid;
                const int r = c >> 2, cc = (c & 3) * 8;
                *(short8*)&sA[r * 32 + cc] = *(const short8*)(Ak + (size_t)r * DF + cc);
                *(short8*)&sB[r * 32 + cc] = *(const short8*)(Bk + (size_t)r * DF + cc);
            }
        } else {
            const float* Ak = Af + kt * 32;
            const float* Bk = Bf + kt * 32;
#pragma unroll
            for (int i = 0; i < 2; ++i) {
                const int c = i * 256 + tid;
                const int r = c >> 2, cc = (c & 3) * 8;
                float4 a0 = *(const float4*)(Ak + (size_t)r * DF + cc);
                float4 a1 = *(const float4*)(Ak + (size_t)r * DF + cc + 4);
                float4 b0 = *(const float4*)(Bk + (size_t)r * DF + cc);
                float4 b1 = *(const float4*)(Bk + (size_t)r * DF + cc + 4);
                short8 sa, sb;
                sa[0]=(short)f2bf(a0.x); sa[1]=(short)f2bf(a0.y);
                sa[2]=(short)f2bf(a0.z); sa[3]=(short)f2bf(a0.w);
                sa[4]=(short)f2bf(a1.x); sa[5]=(short)f2bf(a1.y);
                sa[6]=(short)f2bf(a1.z); sa[7]=(short)f2bf(a1.w);
                sb[0]=(short)f2bf(b0.x); sb[1]=(short)f2bf(b0.y);
                sb[2]=(short)f2bf(b0.z); sb[3]=(short)f2bf(b0.w);
                sb[4]=(short)f2bf(b1.x); sb[5]=(short)f2bf(b1.y);
                sb[6]=(short)f2bf(b1.z); sb[7]=(short)f2bf(b1.w);
                *(short8*)&sA[r * 32 + cc] = sa;
                *(short8*)&sB[r * 32 + cc] = sb;
            }
        }
        __syncthreads();

        const int lr = lane & 15;
        const int lk = (lane >> 4) * 8;
        short8 a[4], b[4];
#pragma unroll
        for (int i = 0; i < 4; i++)
            a[i] = *(const short8*)&sA[(wm * 64 + i * 16 + lr) * 32 + lk];
#pragma unroll
        for (int j = 0; j < 4; j++)
            b[j] = *(const short8*)&sB[(wn * 64 + j * 16 + lr) * 32 + lk];
#pragma unroll
        for (int i = 0; i < 4; i++)
#pragma unroll
            for (int j = 0; j < 4; j++)
                acc[i][j] = __builtin_amdgcn_mfma_f32_16x16x32_bf16(
                    a[i], b[j], acc[i][j], 0, 0, 0);
    }

    const int rb = (lane >> 4) * 4;
#pragma unroll
    for (int i = 0; i < 4; i++)
#pragma unroll
        for (int j = 0; j < 4; j++)
#pragma unroll
            for (int r = 0; r < 4; r++) {
                int row = wm * 64 + i * 16 + rb + r;
                sC[row * 136 + wn * 64 + j * 16 + (lane & 15)] =
                    f2bf(acc[i][j][r] * sPhi[row]);
            }
    __syncthreads();
#pragma unroll
    for (int it = 0; it < 8; ++it) {
        int row = it * 16 + (tid >> 4);
        int col = (tid & 15) * 8;
        uint4 v = *(const uint4*)&sC[row * 136 + col];
        *(uint4*)&Z[((size_t)(tm * 128 + row) * NF + n) * W + (on0 - o0) + col] = v;
    }
}

// ---------------------------------------------------------------------------
// Kernel 2a: chunk sums over CHs rows. grid (nch, NF), block W/2.
// ---------------------------------------------------------------------------
__global__ __launch_bounds__(256, 2) void k_csum(
    const unsigned short* __restrict__ Z, float* __restrict__ Cs,
    int W, int CHs)
{
    const int c = blockIdx.x, n = blockIdx.y, tid = threadIdx.x;
    const unsigned short* p = Z + ((size_t)(c * CHs) * NF + n) * W + tid * 2;
    float sx = 0.f, sy = 0.f;
#pragma unroll 8
    for (int t = 0; t < CHs; ++t) {
        unsigned int u = *(const unsigned int*)(p + (size_t)t * NF * W);
        sx += __uint_as_float(u << 16);
        sy += __uint_as_float(u & 0xffff0000u);
    }
    float2* q = (float2*)&Cs[((size_t)c * NF + n) * W + tid * 2];
    *q = make_float2(sx, sy);
}

// ---------------------------------------------------------------------------
// Kernel 2b: exclusive prefix over chunks + cross-pass carry Gc.
// Wave-per-column shuffle scan (r9: thread-per-column serial loop was
// latency-bound). Block 256 = 4 waves = 4 columns; lane handles K=nch/64
// consecutive chunks; no local arrays (reload pattern) -> no alloca risk.
// grid (NF*(W/2)/4), block 256.  Requires nch <= 512.
// ---------------------------------------------------------------------------
__global__ __launch_bounds__(256, 2) void k_prefix(
    float* __restrict__ Cs, float* __restrict__ Gc, int W, int rr, int nch)
{
    const int tid = threadIdx.x;
    const int wave = tid >> 6, lane = tid & 63;
    const int col = blockIdx.x * 4 + wave;
    const int n = col / (W / 2);
    const int opair = col % (W / 2);
    const int K = (nch + 63) / 64;
    const int c0 = lane * K;

    float carx = 0.f, cary = 0.f;
    if (rr != 0) {
        float2 g = *(const float2*)&Gc[(size_t)n * DOUT + opair * 2];
        carx = g.x; cary = g.y;
    }
    // pass 1: local sums
    float sx = 0.f, sy = 0.f;
    for (int k = 0; k < K; ++k) {
        int c = c0 + k;
        if (c < nch) {
            float2 v = *(const float2*)&Cs[((size_t)c * NF + n) * W + opair * 2];
            sx += v.x; sy += v.y;
        }
    }
    // inclusive wave scan of local sums
    float ix = sx, iy = sy;
    for (int off = 1; off < 64; off <<= 1) {
        float tx = __shfl_up(ix, off);
        float ty = __shfl_up(iy, off);
        if (lane >= off) { ix += tx; iy += ty; }
    }
    // pass 2: rewrite chunks with exclusive prefixes (reload, then store)
    float bx = carx + ix - sx;
    float by = cary + iy - sy;
    for (int k = 0; k < K; ++k) {
        int c = c0 + k;
        if (c < nch) {
            float2* p = (float2*)&Cs[((size_t)c * NF + n) * W + opair * 2];
            float2 v = *p;
            *p = make_float2(bx, by);
            bx += v.x; by += v.y;
        }
    }
    if (lane == 63)
        *(float2*)&Gc[(size_t)n * DOUT + opair * 2] = make_float2(carx + ix, cary + iy);
}

// ---------------------------------------------------------------------------
// Kernel 2c: scan + filter-weighted reduce. Output fp32.
// r6-r9 lesson: 48 floats of loop-carried state per thread ALWAYS spills (the
// backend's occupancy-targeting RA caps ~64 VGPR; scratch ops then share vmcnt
// with Z loads -> full serialization, 48-54 us). Fix: split NF across 4 waves,
// 6 filters/wave -> 12 floats state/thread; LDS-reduce partials per t-step.
// grid (nch, W/128), block 256 = 4 waves x 64 o-pairs.
// ---------------------------------------------------------------------------
#define JLIST(F) F(0) F(1) F(2) F(3) F(4) F(5)

__global__ __launch_bounds__(256, 2) void k_scan(
    const unsigned short* __restrict__ Z, const float* __restrict__ Cs,
    const float* __restrict__ Fw, float* __restrict__ Out,
    int r0, int o0, int W, int CHs)
{
    __shared__ float sPhi[32 * NF];
    __shared__ float2 sP[4][64];
    const int cg = blockIdx.x, tid = threadIdx.x;
    const int g = tid >> 6, op = tid & 63;      // wave id (n-group), o-pair lane
    const int ng0 = g * 6;
    const int opg = blockIdx.y * 64 + op;       // o-pair within W slice
    const int t0g = r0 + cg * CHs;
    const int t0 = t0g & (TT - 1);
    for (int i = tid; i < CHs * NF; i += 256)
        sPhi[i] = Fw[(t0 + i / NF) * NF + (i % NF)];
    __syncthreads();

#define DECLG(j) float gx##j, gy##j;
    JLIST(DECLG)
#define INITG(j) { float2 v = *(const float2*)&Cs[((size_t)cg * NF + ng0 + j) * W + opg * 2]; \
                   gx##j = v.x; gy##j = v.y; }
    JLIST(INITG)

    const unsigned short* zp = Z + ((size_t)cg * CHs * NF + ng0) * W + opg * 2;
    float* outp = Out + (size_t)t0g * DOUT + o0 + blockIdx.y * 128 + op * 2;
    for (int t = 0; t < CHs; ++t) {
        float ax = 0.f, ay = 0.f;
        const float* php = &sPhi[t * NF + ng0];
#define UPDG(j) { unsigned int u = *(const unsigned int*)(zp + (size_t)j * W); \
                  gx##j += __uint_as_float(u << 16); \
                  gy##j += __uint_as_float(u & 0xffff0000u); \
                  float ph = php[j]; ax += ph * gx##j; ay += ph * gy##j; }
        JLIST(UPDG)
        sP[g][op] = make_float2(ax, ay);
        __syncthreads();
        if (g == 0) {
            float2 p0 = sP[0][op], p1 = sP[1][op], p2 = sP[2][op], p3 = sP[3][op];
            *(float2*)outp = make_float2(p0.x + p1.x + p2.x + p3.x,
                                         p0.y + p1.y + p2.y + p3.y);
        }
        __syncthreads();
        zp += (size_t)NF * W;
        outp += DOUT;
    }
}

// ---------------------------------------------------------------------------
extern "C" void kernel_launch(void* const* d_in, const int* in_sizes, int n_in,
                              void* d_out, int out_size, void* d_ws, size_t ws_size,
                              hipStream_t stream)
{
    const void* X = d_in[0]; const void* Fil = d_in[1]; const void* Mw = d_in[2];
    for (int i = 0; i < n_in && i < 3; ++i) {
        if (in_sizes[i] == BQ * TT * DF)        X   = d_in[i];
        else if (in_sizes[i] == TT * NF)        Fil = d_in[i];
        else if (in_sizes[i] == NF * DOUT * DF) Mw  = d_in[i];
    }
    float* Out = (float*)d_out;

    const size_t offF = 256;
    const size_t nbF  = (size_t)TT * NF * 4;
    const size_t off0 = offF + nbF;
    const size_t nbX  = (size_t)BQ * TT * DF * 2;    // 8.39 MB
    const size_t nbM  = (size_t)NF * DOUT * DF * 2;  // 12.58 MB
    const size_t nbGc = (size_t)NF * DOUT * 4;

    int* flag = (int*)d_ws;
    float* Fw = (float*)((char*)d_ws + offF);

    // Fast tier: (RT rows/pass, CHs scan-chunk). Prefer big RT, small CHs.
    static const int rts[5] = {2048, 1024, 512, 256, 128};
    static const int chss[3] = {8, 16, 32};
    int RT = 0, CHs = 32;
    for (int ri = 0; ri < 5 && RT == 0; ++ri)
        for (int ci = 0; ci < 3; ++ci) {
            int rt = rts[ri], ch = chss[ci];
            size_t need = off0 + nbX + nbM
                        + (size_t)rt * NF * 512 * 2
                        + (size_t)(rt / ch) * NF * 512 * 4 + nbGc;
            if (need <= ws_size) { RT = rt; CHs = ch; break; }
        }

    hipLaunchKernelGGL(k_detect, dim3(1), dim3(64), 0, stream,
                       (const unsigned int*)X, flag);
    hipLaunchKernelGGL(k_convf, dim3(192), dim3(256), 0, stream,
                       Fil, Fw, flag, TT * NF);

    if (RT > 0) {
        unsigned short* Xbf = (unsigned short*)((char*)d_ws + off0);
        unsigned short* Mbf = (unsigned short*)((char*)Xbf + nbX);
        unsigned short* Z   = (unsigned short*)((char*)Mbf + nbM);
        float* Cs = (float*)((char*)Z + (size_t)RT * NF * 512 * 2);
        float* Gc = (float*)((char*)Cs + (size_t)(RT / CHs) * NF * 512 * 4);

        hipLaunchKernelGGL(k_convert, dim3(2048), dim3(256), 0, stream,
                           X, Xbf, flag, BQ * TT * DF / 4);
        hipLaunchKernelGGL(k_convert, dim3(3072), dim3(256), 0, stream,
                           Mw, Mbf, flag, NF * DOUT * DF / 4);

        const int nrr = TT / RT, nch = RT / CHs;
        for (int b = 0; b < BQ; ++b) {
            for (int rr = 0; rr < nrr; ++rr) {
                const int r0 = b * TT + rr * RT;
                hipLaunchKernelGGL(k_gemm_fast, dim3(RT / 128, 4, NF), dim3(256),
                                   0, stream, Xbf, Mbf, Fw, Z, r0);
                hipLaunchKernelGGL(k_csum, dim3(nch, NF), dim3(256), 0, stream,
                                   Z, Cs, 512, CHs);
                hipLaunchKernelGGL(k_prefix, dim3(NF * 256 / 4), dim3(256), 0, stream,
                                   Cs, Gc, 512, rr, nch);
                hipLaunchKernelGGL(k_scan, dim3(nch, 4), dim3(256), 0, stream,
                                   Z, Cs, Fw, Out, r0, 0, 512, CHs);
            }
        }
        return;
    }

    // Slow tiers (tiny ws): in-kernel convert GEMM, o-sliced, CH=32.
    static const int cRT[7] = {2048, 1024, 512, 256, 128, 128, 128};
    static const int cW[7]  = {512, 512, 512, 512, 512, 256, 128};
    int RTs = 128, W = 128;
    for (int ci = 0; ci < 7; ++ci) {
        size_t need = off0 + (size_t)cRT[ci] * NF * cW[ci] * 2
                    + (size_t)(cRT[ci] / 32) * NF * cW[ci] * 4 + nbGc;
        if (need <= ws_size) { RTs = cRT[ci]; W = cW[ci]; break; }
    }
    unsigned short* Z = (unsigned short*)((char*)d_ws + off0);
    float* Cs = (float*)((char*)Z + (size_t)RTs * NF * W * 2);
    float* Gc = (float*)((char*)Cs + (size_t)(RTs / 32) * NF * W * 4);

    const int nrr = TT / RTs, nch = RTs / 32;
    for (int b = 0; b < BQ; ++b) {
        for (int o0 = 0; o0 < DOUT; o0 += W) {
            for (int rr = 0; rr < nrr; ++rr) {
                const int r0 = b * TT + rr * RTs;
                hipLaunchKernelGGL(k_gemm, dim3(RTs / 128, W / 128, NF), dim3(256),
                                   0, stream, X, Mw, Fil, flag, Z, r0, o0, W);
                hipLaunchKernelGGL(k_csum, dim3(nch, NF), dim3(W / 2), 0, stream,
                                   Z, Cs, W, 32);
                hipLaunchKernelGGL(k_prefix, dim3(NF * (W / 2) / 4), dim3(256), 0, stream,
                                   Cs, Gc, W, rr, nch);
                hipLaunchKernelGGL(k_scan, dim3(nch, W / 128), dim3(256), 0, stream,
                                   Z, Cs, Fw, Out, r0, o0, W, 32);
            }
        }
    }
}

// Round 11
// 423.315 us; speedup vs baseline: 1.5419x; 1.0818x over previous
//
#include <hip/hip_runtime.h>
#include <stdint.h>

// Problem: B=4, T=2048, D_IN=512, D_OUT=512, N_FILT=24.
// Inputs fp32 (runtime-detected, bf16 fallback). Output fp32.
// out[b,t,o] = sum_n phi[t,n] * cumsum_t( phi[t,n] * (M[n] @ x[b,t,:]) )[o]
#define BQ 4
#define TT 2048
#define DF 512
#define DOUT 512
#define NF 24
#define CHF 8   // fast-path scan chunk (rows)

typedef __attribute__((ext_vector_type(8))) short short8;
typedef __attribute__((ext_vector_type(4))) float f32x4;

typedef __attribute__((address_space(3))) uint8_t       lds_u8;
typedef __attribute__((address_space(1))) const uint8_t glb_u8;

__device__ __forceinline__ float bf2f(unsigned short u) {
    union { unsigned int i; float f; } v; v.i = ((unsigned int)u) << 16; return v.f;
}
__device__ __forceinline__ unsigned short f2bf(float f) {
    union { float f; unsigned int i; } v; v.f = f;
    unsigned int r = v.i + 0x7FFFu + ((v.i >> 16) & 1u);  // RNE
    return (unsigned short)(r >> 16);
}
__device__ __forceinline__ float lo16f(unsigned int u) { return __uint_as_float(u << 16); }
__device__ __forceinline__ float hi16f(unsigned int u) { return __uint_as_float(u & 0xffff0000u); }

// ---------------------------------------------------------------------------
// Dtype sniffer (flag=1 => fp32 inputs).
// ---------------------------------------------------------------------------
__device__ __forceinline__ int plaus16(unsigned int h) {
    unsigned int e = (h >> 7) & 0xffu;
    return (e >= 97u && e <= 141u) || ((h & 0x7fffu) == 0u);
}

__global__ void k_detect(const unsigned int* __restrict__ X, int* __restrict__ flag)
{
    const int lane = threadIdx.x;  // 64 threads, 1 block
    int cnt = 0;
#pragma unroll
    for (int i = 0; i < 4; ++i) {
        unsigned int w = X[lane * 4 + i];
        cnt += (plaus16(w >> 16) && plaus16(w & 0xffffu)) ? 1 : 0;
    }
    for (int off = 32; off > 0; off >>= 1) cnt += __shfl_down(cnt, off);
    if (lane == 0) *flag = (cnt < 180) ? 1 : 0;
}

// ---------------------------------------------------------------------------
// One-time conversions: X/M -> bf16 workspace copies, filters -> fp32.
// ---------------------------------------------------------------------------
__global__ __launch_bounds__(256) void k_convert(
    const void* __restrict__ src, unsigned short* __restrict__ dst,
    const int* __restrict__ flag, int n4)
{
    const int isf32 = *flag;
    int i = blockIdx.x * 256 + threadIdx.x;
    const int stride = gridDim.x * 256;
    for (; i < n4; i += stride) {
        ushort4 o;
        if (isf32) {
            float4 v = ((const float4*)src)[i];
            o.x = f2bf(v.x); o.y = f2bf(v.y); o.z = f2bf(v.z); o.w = f2bf(v.w);
        } else {
            o = ((const ushort4*)src)[i];
        }
        ((ushort4*)dst)[i] = o;
    }
}

__global__ __launch_bounds__(256) void k_convf(
    const void* __restrict__ src, float* __restrict__ dst,
    const int* __restrict__ flag, int n)
{
    const int isf32 = *flag;
    int i = blockIdx.x * 256 + threadIdx.x;
    const int stride = gridDim.x * 256;
    for (; i < n; i += stride)
        dst[i] = isf32 ? ((const float*)src)[i]
                       : bf2f(((const unsigned short*)src)[i]);
}

// ---------------------------------------------------------------------------
// FAST GEMM, fused chunk-sums. m97 pattern + XOR bank swizzle (r10: 3.3M
// conflict cycles from 8-way aliasing on fragment reads; q -> q^((row>>1)&3)
// spreads the bank quads; staging permutes lane->global-chunk only, so the
// per-wave address set & the wave-uniform LDS dst are unchanged).
// Epilogue also emits Cs chunk sums (CHF=8) from the bf16 sC tile —
// bit-identical numerics to the old k_csum, saves a full Z re-read.
// grid (rows/128, 4, NF), block 256.
// ---------------------------------------------------------------------------
__global__ __launch_bounds__(256, 2) void k_gemm_fast(
    const unsigned short* __restrict__ X,   // bf16 [B*T, DF]
    const unsigned short* __restrict__ Mw,  // bf16 [NF][DOUT][DF]
    const float* __restrict__ Fw,           // fp32 [TT][NF]
    unsigned short* __restrict__ Z,         // bf16 [rl][n][512]
    float* __restrict__ Cs,                 // fp32 [chunk][n][512]
    int r0)
{
    __shared__ unsigned short sA[128 * 32];
    __shared__ unsigned short sB[128 * 32];
    __shared__ unsigned short sC[128 * 136];
    __shared__ float sPhi[128];

    const int tid  = threadIdx.x;
    const int lane = tid & 63;
    const int w    = tid >> 6;
    const int wm   = w & 1, wn = w >> 1;
    const int tm   = blockIdx.x;
    const int on0  = blockIdx.y * 128;
    const int n    = blockIdx.z;

    const int rowg0 = r0 + tm * 128;
    if (tid < 128)
        sPhi[tid] = Fw[((rowg0 + tid) & (TT - 1)) * NF + n];

    const unsigned short* Ag = X + (size_t)rowg0 * DF;
    const unsigned short* Bg = Mw + (size_t)n * DOUT * DF + (size_t)on0 * DF;

    f32x4 acc[4][4];
#pragma unroll
    for (int i = 0; i < 4; i++)
#pragma unroll
        for (int j = 0; j < 4; j++) acc[i][j] = (f32x4){0.f, 0.f, 0.f, 0.f};

    for (int kt = 0; kt < DF / 32; ++kt) {
        __syncthreads();
        const unsigned short* Ak = Ag + kt * 32;
        const unsigned short* Bk = Bg + kt * 32;
#pragma unroll
        for (int i = 0; i < 2; ++i) {
            const int cbase = i * 256 + w * 64;   // wave-uniform 16B-slot base
            const int c = cbase + lane;           // this lane's LDS slot
            const int r = c >> 2, qs = c & 3;
            const int qg = qs ^ ((r >> 1) & 3);   // swizzle: slot qs holds chunk qg
            __builtin_amdgcn_global_load_lds(
                (const glb_u8*)(Ak + (size_t)r * DF + qg * 8),
                (lds_u8*)sA + cbase * 16, 16, 0, 0);
            __builtin_amdgcn_global_load_lds(
                (const glb_u8*)(Bk + (size_t)r * DF + qg * 8),
                (lds_u8*)sB + cbase * 16, 16, 0, 0);
        }
        __syncthreads();

        const int lr = lane & 15;
        const int q  = lane >> 4;
        const int qsw = (q ^ ((lr >> 1) & 3)) * 8;  // (row>>1)&3 == (lr>>1)&3
        short8 a[4], b[4];
#pragma unroll
        for (int i = 0; i < 4; i++)
            a[i] = *(const short8*)&sA[(wm * 64 + i * 16 + lr) * 32 + qsw];
#pragma unroll
        for (int j = 0; j < 4; j++)
            b[j] = *(const short8*)&sB[(wn * 64 + j * 16 + lr) * 32 + qsw];
#pragma unroll
        for (int i = 0; i < 4; i++)
#pragma unroll
            for (int j = 0; j < 4; j++)
                acc[i][j] = __builtin_amdgcn_mfma_f32_16x16x32_bf16(
                    a[i], b[j], acc[i][j], 0, 0, 0);
    }

    // C/D layout (m89/m91-verified): col = lane&15, row = (lane>>4)*4 + reg
    const int rb = (lane >> 4) * 4;
#pragma unroll
    for (int i = 0; i < 4; i++)
#pragma unroll
        for (int j = 0; j < 4; j++)
#pragma unroll
            for (int r = 0; r < 4; r++) {
                int row = wm * 64 + i * 16 + rb + r;
                sC[row * 136 + wn * 64 + j * 16 + (lane & 15)] =
                    f2bf(acc[i][j][r] * sPhi[row]);
            }
    __syncthreads();

    // Z store (coalesced 16B)
#pragma unroll
    for (int it = 0; it < 8; ++it) {
        int row = it * 16 + (tid >> 4);
        int col = (tid & 15) * 8;
        uint4 v = *(const uint4*)&sC[row * 136 + col];
        *(uint4*)&Z[((size_t)(tm * 128 + row) * NF + n) * 512 + on0 + col] = v;
    }

    // Fused chunk sums: 16 chunks x 128 cols; thread -> (chunk ci, 8 cols).
    {
        const int ci  = tid >> 4;           // chunk within tile, 0..15
        const int col = (tid & 15) * 8;
        float s0=0.f,s1=0.f,s2=0.f,s3=0.f,s4=0.f,s5=0.f,s6=0.f,s7=0.f;
#pragma unroll
        for (int r = 0; r < CHF; ++r) {
            uint4 v = *(const uint4*)&sC[(ci * CHF + r) * 136 + col];
            s0 += lo16f(v.x); s1 += hi16f(v.x);
            s2 += lo16f(v.y); s3 += hi16f(v.y);
            s4 += lo16f(v.z); s5 += hi16f(v.z);
            s6 += lo16f(v.w); s7 += hi16f(v.w);
        }
        float* cp = &Cs[((size_t)(tm * 16 + ci) * NF + n) * 512 + on0 + col];
        *(float4*)cp       = make_float4(s0, s1, s2, s3);
        *(float4*)(cp + 4) = make_float4(s4, s5, s6, s7);
    }
}

// ---------------------------------------------------------------------------
// SLOW GEMM (fallback for tiny ws): register staging + in-flight convert.
// ---------------------------------------------------------------------------
__global__ __launch_bounds__(256, 2) void k_gemm(
    const void* __restrict__ Xv, const void* __restrict__ Mv,
    const void* __restrict__ Fv, const int* __restrict__ flag,
    unsigned short* __restrict__ Z, int r0, int o0, int W)
{
    __shared__ unsigned short sA[128 * 32];
    __shared__ unsigned short sB[128 * 32];
    __shared__ unsigned short sC[128 * 136];
    __shared__ float sPhi[128];

    const int isf32 = *flag;
    const int tid  = threadIdx.x;
    const int lane = tid & 63;
    const int w    = tid >> 6;
    const int wm   = w & 1, wn = w >> 1;
    const int tm   = blockIdx.x;
    const int on0  = o0 + blockIdx.y * 128;
    const int n    = blockIdx.z;

    const int rowg0 = r0 + tm * 128;
    if (tid < 128) {
        int t = (rowg0 + tid) & (TT - 1);
        sPhi[tid] = isf32 ? ((const float*)Fv)[t * NF + n]
                          : bf2f(((const unsigned short*)Fv)[t * NF + n]);
    }

    const unsigned short* Ah = (const unsigned short*)Xv + (size_t)rowg0 * DF;
    const unsigned short* Bh = (const unsigned short*)Mv +
        (size_t)n * DOUT * DF + (size_t)on0 * DF;
    const float* Af = (const float*)Xv + (size_t)rowg0 * DF;
    const float* Bf = (const float*)Mv + (size_t)n * DOUT * DF + (size_t)on0 * DF;

    f32x4 acc[4][4];
#pragma unroll
    for (int i = 0; i < 4; i++)
#pragma unroll
        for (int j = 0; j < 4; j++) acc[i][j] = (f32x4){0.f, 0.f, 0.f, 0.f};

    for (int kt = 0; kt < DF / 32; ++kt) {
        __syncthreads();
        if (!isf32) {
            const unsigned short* Ak = Ah + kt * 32;
            const unsigned short* Bk = Bh + kt * 32;
#pragma unroll
            for (int i = 0; i < 2; ++i) {
                const int c = i * 256 + tid;
                const int r = c >> 2, cc = (c & 3) * 8;
                *(short8*)&sA[r * 32 + cc] = *(const short8*)(Ak + (size_t)r * DF + cc);
                *(short8*)&sB[r * 32 + cc] = *(const short8*)(Bk + (size_t)r * DF + cc);
            }
        } else {
            const float* Ak = Af + kt * 32;
            const float* Bk = Bf + kt * 32;
#pragma unroll
            for (int i = 0; i < 2; ++i) {
                const int c = i * 256 + tid;
                const int r = c >> 2, cc = (c & 3) * 8;
                float4 a0 = *(const float4*)(Ak + (size_t)r * DF + cc);
                float4 a1 = *(const float4*)(Ak + (size_t)r * DF + cc + 4);
                float4 b0 = *(const float4*)(Bk + (size_t)r * DF + cc);
                float4 b1 = *(const float4*)(Bk + (size_t)r * DF + cc + 4);
                short8 sa, sb;
                sa[0]=(short)f2bf(a0.x); sa[1]=(short)f2bf(a0.y);
                sa[2]=(short)f2bf(a0.z); sa[3]=(short)f2bf(a0.w);
                sa[4]=(short)f2bf(a1.x); sa[5]=(short)f2bf(a1.y);
                sa[6]=(short)f2bf(a1.z); sa[7]=(short)f2bf(a1.w);
                sb[0]=(short)f2bf(b0.x); sb[1]=(short)f2bf(b0.y);
                sb[2]=(short)f2bf(b0.z); sb[3]=(short)f2bf(b0.w);
                sb[4]=(short)f2bf(b1.x); sb[5]=(short)f2bf(b1.y);
                sb[6]=(short)f2bf(b1.z); sb[7]=(short)f2bf(b1.w);
                *(short8*)&sA[r * 32 + cc] = sa;
                *(short8*)&sB[r * 32 + cc] = sb;
            }
        }
        __syncthreads();

        const int lr = lane & 15;
        const int lk = (lane >> 4) * 8;
        short8 a[4], b[4];
#pragma unroll
        for (int i = 0; i < 4; i++)
            a[i] = *(const short8*)&sA[(wm * 64 + i * 16 + lr) * 32 + lk];
#pragma unroll
        for (int j = 0; j < 4; j++)
            b[j] = *(const short8*)&sB[(wn * 64 + j * 16 + lr) * 32 + lk];
#pragma unroll
        for (int i = 0; i < 4; i++)
#pragma unroll
            for (int j = 0; j < 4; j++)
                acc[i][j] = __builtin_amdgcn_mfma_f32_16x16x32_bf16(
                    a[i], b[j], acc[i][j], 0, 0, 0);
    }

    const int rb = (lane >> 4) * 4;
#pragma unroll
    for (int i = 0; i < 4; i++)
#pragma unroll
        for (int j = 0; j < 4; j++)
#pragma unroll
            for (int r = 0; r < 4; r++) {
                int row = wm * 64 + i * 16 + rb + r;
                sC[row * 136 + wn * 64 + j * 16 + (lane & 15)] =
                    f2bf(acc[i][j][r] * sPhi[row]);
            }
    __syncthreads();
#pragma unroll
    for (int it = 0; it < 8; ++it) {
        int row = it * 16 + (tid >> 4);
        int col = (tid & 15) * 8;
        uint4 v = *(const uint4*)&sC[row * 136 + col];
        *(uint4*)&Z[((size_t)(tm * 128 + row) * NF + n) * W + (on0 - o0) + col] = v;
    }
}

// ---------------------------------------------------------------------------
// Kernel 2a (slow tier only): chunk sums. grid (nch, NF), block W/2.
// ---------------------------------------------------------------------------
__global__ __launch_bounds__(256, 2) void k_csum(
    const unsigned short* __restrict__ Z, float* __restrict__ Cs,
    int W, int CHs)
{
    const int c = blockIdx.x, n = blockIdx.y, tid = threadIdx.x;
    const unsigned short* p = Z + ((size_t)(c * CHs) * NF + n) * W + tid * 2;
    float sx = 0.f, sy = 0.f;
#pragma unroll 8
    for (int t = 0; t < CHs; ++t) {
        unsigned int u = *(const unsigned int*)(p + (size_t)t * NF * W);
        sx += lo16f(u);
        sy += hi16f(u);
    }
    float2* q = (float2*)&Cs[((size_t)c * NF + n) * W + tid * 2];
    *q = make_float2(sx, sy);
}

// ---------------------------------------------------------------------------
// Kernel 2b: exclusive prefix over chunks (+ cross-pass carry Gc, nbat==1).
// Wave-per-column shuffle scan; 4 waves/block. grid (nbat*NF*(W/2)/4).
// ---------------------------------------------------------------------------
__global__ __launch_bounds__(256, 2) void k_prefix(
    float* __restrict__ Cs, float* __restrict__ Gc,
    int W, int rr, int nch, int nbat)
{
    const int tid = threadIdx.x;
    const int wave = tid >> 6, lane = tid & 63;
    const int col = blockIdx.x * 4 + wave;
    const int colsPerB = NF * (W / 2);
    const int b = col / colsPerB;
    const int rest = col % colsPerB;
    const int n = rest / (W / 2);
    const int opair = rest % (W / 2);
    float* CsB = Cs + (size_t)b * nch * NF * W;
    const int K = (nch + 63) / 64;
    const int c0 = lane * K;

    float carx = 0.f, cary = 0.f;
    if (nbat == 1 && rr != 0) {
        float2 g = *(const float2*)&Gc[(size_t)n * DOUT + opair * 2];
        carx = g.x; cary = g.y;
    }
    float sx = 0.f, sy = 0.f;
    for (int k = 0; k < K; ++k) {
        int c = c0 + k;
        if (c < nch) {
            float2 v = *(const float2*)&CsB[((size_t)c * NF + n) * W + opair * 2];
            sx += v.x; sy += v.y;
        }
    }
    float ix = sx, iy = sy;
    for (int off = 1; off < 64; off <<= 1) {
        float tx = __shfl_up(ix, off);
        float ty = __shfl_up(iy, off);
        if (lane >= off) { ix += tx; iy += ty; }
    }
    float bx = carx + ix - sx;
    float by = cary + iy - sy;
    for (int k = 0; k < K; ++k) {
        int c = c0 + k;
        if (c < nch) {
            float2* p = (float2*)&CsB[((size_t)c * NF + n) * W + opair * 2];
            float2 v = *p;
            *p = make_float2(bx, by);
            bx += v.x; by += v.y;
        }
    }
    if (nbat == 1 && lane == 63)
        *(float2*)&Gc[(size_t)n * DOUT + opair * 2] = make_float2(carx + ix, cary + iy);
}

// ---------------------------------------------------------------------------
// Kernel 2c: scan + filter-weighted reduce. 4 waves x 6 filters (r9 fix:
// 12 floats state/thread fits the RA's occupancy budget; LDS-reduce per t).
// grid (nch_total, W/128), block 256.
// ---------------------------------------------------------------------------
#define JLIST(F) F(0) F(1) F(2) F(3) F(4) F(5)

__global__ __launch_bounds__(256, 2) void k_scan(
    const unsigned short* __restrict__ Z, const float* __restrict__ Cs,
    const float* __restrict__ Fw, float* __restrict__ Out,
    int r0, int o0, int W, int CHs)
{
    __shared__ float sPhi[32 * NF];
    __shared__ float2 sP[4][64];
    const int cg = blockIdx.x, tid = threadIdx.x;
    const int g = tid >> 6, op = tid & 63;
    const int ng0 = g * 6;
    const int opg = blockIdx.y * 64 + op;
    const int t0g = r0 + cg * CHs;
    const int t0 = t0g & (TT - 1);
    for (int i = tid; i < CHs * NF; i += 256)
        sPhi[i] = Fw[(t0 + i / NF) * NF + (i % NF)];
    __syncthreads();

#define DECLG(j) float gx##j, gy##j;
    JLIST(DECLG)
#define INITG(j) { float2 v = *(const float2*)&Cs[((size_t)cg * NF + ng0 + j) * W + opg * 2]; \
                   gx##j = v.x; gy##j = v.y; }
    JLIST(INITG)

    const unsigned short* zp = Z + ((size_t)cg * CHs * NF + ng0) * W + opg * 2;
    float* outp = Out + (size_t)t0g * DOUT + o0 + blockIdx.y * 128 + op * 2;
    for (int t = 0; t < CHs; ++t) {
        float ax = 0.f, ay = 0.f;
        const float* php = &sPhi[t * NF + ng0];
#define UPDG(j) { unsigned int u = *(const unsigned int*)(zp + (size_t)j * W); \
                  gx##j += lo16f(u); gy##j += hi16f(u); \
                  float ph = php[j]; ax += ph * gx##j; ay += ph * gy##j; }
        JLIST(UPDG)
        sP[g][op] = make_float2(ax, ay);
        __syncthreads();
        if (g == 0) {
            float2 p0 = sP[0][op], p1 = sP[1][op], p2 = sP[2][op], p3 = sP[3][op];
            *(float2*)outp = make_float2(p0.x + p1.x + p2.x + p3.x,
                                         p0.y + p1.y + p2.y + p3.y);
        }
        __syncthreads();
        zp += (size_t)NF * W;
        outp += DOUT;
    }
}

// ---------------------------------------------------------------------------
extern "C" void kernel_launch(void* const* d_in, const int* in_sizes, int n_in,
                              void* d_out, int out_size, void* d_ws, size_t ws_size,
                              hipStream_t stream)
{
    const void* X = d_in[0]; const void* Fil = d_in[1]; const void* Mw = d_in[2];
    for (int i = 0; i < n_in && i < 3; ++i) {
        if (in_sizes[i] == BQ * TT * DF)        X   = d_in[i];
        else if (in_sizes[i] == TT * NF)        Fil = d_in[i];
        else if (in_sizes[i] == NF * DOUT * DF) Mw  = d_in[i];
    }
    float* Out = (float*)d_out;

    const size_t offF = 256;
    const size_t nbF  = (size_t)TT * NF * 4;
    const size_t off0 = offF + nbF;
    const size_t nbX  = (size_t)BQ * TT * DF * 2;    // 8.39 MB
    const size_t nbM  = (size_t)NF * DOUT * DF * 2;  // 12.58 MB
    const size_t nbGc = (size_t)NF * DOUT * 4;

    int* flag = (int*)d_ws;
    float* Fw = (float*)((char*)d_ws + offF);

    hipLaunchKernelGGL(k_detect, dim3(1), dim3(64), 0, stream,
                       (const unsigned int*)X, flag);
    hipLaunchKernelGGL(k_convf, dim3(192), dim3(256), 0, stream,
                       Fil, Fw, flag, TT * NF);

    // ---- Mega tier: all 4 batches in one pass (Z 201 MB + Cs 50 MB) ----
    {
        const size_t zB  = (size_t)BQ * TT * NF * 512 * 2;
        const size_t csB = (size_t)(BQ * TT / CHF) * NF * 512 * 4;
        if (off0 + nbX + nbM + zB + csB <= ws_size) {
            unsigned short* Xbf = (unsigned short*)((char*)d_ws + off0);
            unsigned short* Mbf = (unsigned short*)((char*)Xbf + nbX);
            unsigned short* Z   = (unsigned short*)((char*)Mbf + nbM);
            float* Cs = (float*)((char*)Z + zB);

            hipLaunchKernelGGL(k_convert, dim3(2048), dim3(256), 0, stream,
                               X, Xbf, flag, BQ * TT * DF / 4);
            hipLaunchKernelGGL(k_convert, dim3(3072), dim3(256), 0, stream,
                               Mw, Mbf, flag, NF * DOUT * DF / 4);

            const int nch = TT / CHF;            // per batch: 256
            hipLaunchKernelGGL(k_gemm_fast, dim3(BQ * TT / 128, 4, NF), dim3(256),
                               0, stream, Xbf, Mbf, Fw, Z, Cs, 0);
            hipLaunchKernelGGL(k_prefix, dim3(BQ * NF * 256 / 4), dim3(256),
                               0, stream, Cs, (float*)nullptr, 512, 0, nch, BQ);
            hipLaunchKernelGGL(k_scan, dim3(BQ * nch, 4), dim3(256), 0, stream,
                               Z, Cs, Fw, Out, 0, 0, 512, CHF);
            return;
        }
    }

    // ---- Per-batch fused tier (proven >= 84 MB fits RT=2048) ----
    {
        static const int rts[5] = {2048, 1024, 512, 256, 128};
        int RT = 0;
        for (int ri = 0; ri < 5; ++ri) {
            size_t need = off0 + nbX + nbM
                        + (size_t)rts[ri] * NF * 512 * 2
                        + (size_t)(rts[ri] / CHF) * NF * 512 * 4 + nbGc;
            if (need <= ws_size) { RT = rts[ri]; break; }
        }
        if (RT > 0) {
            unsigned short* Xbf = (unsigned short*)((char*)d_ws + off0);
            unsigned short* Mbf = (unsigned short*)((char*)Xbf + nbX);
            unsigned short* Z   = (unsigned short*)((char*)Mbf + nbM);
            float* Cs = (float*)((char*)Z + (size_t)RT * NF * 512 * 2);
            float* Gc = (float*)((char*)Cs + (size_t)(RT / CHF) * NF * 512 * 4);

            hipLaunchKernelGGL(k_convert, dim3(2048), dim3(256), 0, stream,
                               X, Xbf, flag, BQ * TT * DF / 4);
            hipLaunchKernelGGL(k_convert, dim3(3072), dim3(256), 0, stream,
                               Mw, Mbf, flag, NF * DOUT * DF / 4);

            const int nrr = TT / RT, nch = RT / CHF;
            for (int b = 0; b < BQ; ++b) {
                for (int rr = 0; rr < nrr; ++rr) {
                    const int r0 = b * TT + rr * RT;
                    hipLaunchKernelGGL(k_gemm_fast, dim3(RT / 128, 4, NF), dim3(256),
                                       0, stream, Xbf, Mbf, Fw, Z, Cs, r0);
                    hipLaunchKernelGGL(k_prefix, dim3(NF * 256 / 4), dim3(256),
                                       0, stream, Cs, Gc, 512, rr, nch, 1);
                    hipLaunchKernelGGL(k_scan, dim3(nch, 4), dim3(256), 0, stream,
                                       Z, Cs, Fw, Out, r0, 0, 512, CHF);
                }
            }
            return;
        }
    }

    // ---- Slow tiers (tiny ws): in-kernel convert GEMM, o-sliced, CH=32 ----
    static const int cRT[7] = {2048, 1024, 512, 256, 128, 128, 128};
    static const int cW[7]  = {512, 512, 512, 512, 512, 256, 128};
    int RTs = 128, W = 128;
    for (int ci = 0; ci < 7; ++ci) {
        size_t need = off0 + (size_t)cRT[ci] * NF * cW[ci] * 2
                    + (size_t)(cRT[ci] / 32) * NF * cW[ci] * 4 + nbGc;
        if (need <= ws_size) { RTs = cRT[ci]; W = cW[ci]; break; }
    }
    unsigned short* Z = (unsigned short*)((char*)d_ws + off0);
    float* Cs = (float*)((char*)Z + (size_t)RTs * NF * W * 2);
    float* Gc = (float*)((char*)Cs + (size_t)(RTs / 32) * NF * W * 4);

    const int nrr = TT / RTs, nch = RTs / 32;
    for (int b = 0; b < BQ; ++b) {
        for (int o0 = 0; o0 < DOUT; o0 += W) {
            for (int rr = 0; rr < nrr; ++rr) {
                const int r0 = b * TT + rr * RTs;
                hipLaunchKernelGGL(k_gemm, dim3(RTs / 128, W / 128, NF), dim3(256),
                                   0, stream, X, Mw, Fil, flag, Z, r0, o0, W);
                hipLaunchKernelGGL(k_csum, dim3(nch, NF), dim3(W / 2), 0, stream,
                                   Z, Cs, W, 32);
                hipLaunchKernelGGL(k_prefix, dim3(NF * (W / 2) / 4), dim3(256),
                                   0, stream, Cs, Gc, W, rr, nch, 1);
                hipLaunchKernelGGL(k_scan, dim3(nch, W / 128), dim3(256), 0, stream,
                                   Z, Cs, Fw, Out, r0, o0, W, 32);
            }
        }
    }
}